// Round 1
// baseline (7584.342 us; speedup 1.0000x reference)
//
#include <hip/hip_runtime.h>
#include <math.h>

#define TPB 256
static inline int cdiv(int a, int b) { return (a + b - 1) / b; }

// ---------------------------------------------------------------------------
// EfficientDet head on MI355X. Round 0: correctness-first fp32 direct kernels.
// Layouts: all feature maps NCHW fp32. B=4, BiFPN width W=88.
// Levels l=0..4 -> P3..P7, H = {64,32,16,8,4}.
// ---------------------------------------------------------------------------

// 1x1 lateral conv: out[n,co,p] = b[co] + sum_ci x[n,ci,p]*w[co,ci]
__global__ void lateral_k(const float* __restrict__ x, const float* __restrict__ w,
                          const float* __restrict__ b, float* __restrict__ out,
                          int Cin, int HW, int total) {
    int idx = blockIdx.x * blockDim.x + threadIdx.x;
    if (idx >= total) return;
    int p  = idx % HW;
    int co = (idx / HW) % 88;
    int n  = idx / (HW * 88);
    const float* xp = x + (size_t)n * Cin * HW + p;
    const float* wp = w + co * Cin;
    float acc = b[co];
    for (int ci = 0; ci < Cin; ++ci) acc = fmaf(xp[(size_t)ci * HW], wp[ci], acc);
    out[idx] = acc;
}

// fused = (w0*a + w1*up2(bs)) / (w0+w1+eps); a is HxH, bs is (H/2)x(H/2)
__global__ void fuse2_up_k(const float* __restrict__ a, const float* __restrict__ bs,
                           const float* __restrict__ fw, float* __restrict__ out,
                           int H, int total) {
    int idx = blockIdx.x * blockDim.x + threadIdx.x;
    if (idx >= total) return;
    float w0 = fmaxf(fw[0], 0.f), w1 = fmaxf(fw[1], 0.f);
    float inv = 1.f / (w0 + w1 + 1e-4f);
    int x  = idx % H;
    int y  = (idx / H) % H;
    int nc = idx / (H * H);
    int Hh = H >> 1;
    float bv = bs[(size_t)nc * Hh * Hh + (y >> 1) * Hh + (x >> 1)];
    out[idx] = (w0 * a[idx] + w1 * bv) * inv;
}

// fused = (w0*a + w1*down2(bb)) / (w0+w1+eps); a is HxH, bb is 2Hx2H (2x2 maxpool)
__global__ void fuse2_down_k(const float* __restrict__ a, const float* __restrict__ bb,
                             const float* __restrict__ fw, float* __restrict__ out,
                             int H, int total) {
    int idx = blockIdx.x * blockDim.x + threadIdx.x;
    if (idx >= total) return;
    float w0 = fmaxf(fw[0], 0.f), w1 = fmaxf(fw[1], 0.f);
    float inv = 1.f / (w0 + w1 + 1e-4f);
    int x  = idx % H;
    int y  = (idx / H) % H;
    int nc = idx / (H * H);
    int H2 = H * 2;
    const float* bp = bb + (size_t)nc * H2 * H2 + (2 * y) * H2 + 2 * x;
    float m = fmaxf(fmaxf(bp[0], bp[1]), fmaxf(bp[H2], bp[H2 + 1]));
    out[idx] = (w0 * a[idx] + w1 * m) * inv;
}

// fused = (w0*a + w1*b2 + w2*down2(cb)) / (w0+w1+w2+eps); a,b2 HxH, cb 2Hx2H
__global__ void fuse3_down_k(const float* __restrict__ a, const float* __restrict__ b2,
                             const float* __restrict__ cb, const float* __restrict__ fw,
                             float* __restrict__ out, int H, int total) {
    int idx = blockIdx.x * blockDim.x + threadIdx.x;
    if (idx >= total) return;
    float w0 = fmaxf(fw[0], 0.f), w1 = fmaxf(fw[1], 0.f), w2 = fmaxf(fw[2], 0.f);
    float inv = 1.f / (w0 + w1 + w2 + 1e-4f);
    int x  = idx % H;
    int y  = (idx / H) % H;
    int nc = idx / (H * H);
    int H2 = H * 2;
    const float* cp = cb + (size_t)nc * H2 * H2 + (2 * y) * H2 + 2 * x;
    float m = fmaxf(fmaxf(cp[0], cp[1]), fmaxf(cp[H2], cp[H2 + 1]));
    out[idx] = (w0 * a[idx] + w1 * b2[idx] + w2 * m) * inv;
}

// depthwise 3x3, SAME, no bias/act. w: [88][3][3]
__global__ void dw3x3_k(const float* __restrict__ in, const float* __restrict__ w,
                        float* __restrict__ out, int H, int total) {
    int idx = blockIdx.x * blockDim.x + threadIdx.x;
    if (idx >= total) return;
    int x = idx % H;
    int y = (idx / H) % H;
    int c = (idx / (H * H)) % 88;
    int n = idx / (H * H * 88);
    const float* wp = w + c * 9;
    const float* ic = in + ((size_t)(n * 88 + c) * H + y) * H + x;
    bool vx0 = x > 0, vx2 = x < H - 1, vy0 = y > 0, vy2 = y < H - 1;
    float acc = 0.f;
    acc = fmaf((vy0 && vx0) ? ic[-H - 1] : 0.f, wp[0], acc);
    acc = fmaf(vy0 ? ic[-H] : 0.f, wp[1], acc);
    acc = fmaf((vy0 && vx2) ? ic[-H + 1] : 0.f, wp[2], acc);
    acc = fmaf(vx0 ? ic[-1] : 0.f, wp[3], acc);
    acc = fmaf(ic[0], wp[4], acc);
    acc = fmaf(vx2 ? ic[1] : 0.f, wp[5], acc);
    acc = fmaf((vy2 && vx0) ? ic[H - 1] : 0.f, wp[6], acc);
    acc = fmaf(vy2 ? ic[H] : 0.f, wp[7], acc);
    acc = fmaf((vy2 && vx2) ? ic[H + 1] : 0.f, wp[8], acc);
    out[idx] = acc;
}

// pointwise 88->88 + bias + relu. w: [88co][88ci]
__global__ void pw_relu_k(const float* __restrict__ in, const float* __restrict__ w,
                          const float* __restrict__ b, float* __restrict__ out,
                          int HW, int total) {
    int idx = blockIdx.x * blockDim.x + threadIdx.x;
    if (idx >= total) return;
    int p  = idx % HW;
    int co = (idx / HW) % 88;
    int n  = idx / (HW * 88);
    const float* ip = in + (size_t)n * 88 * HW + p;
    const float* wp = w + co * 88;
    float acc = b[co];
    for (int ci = 0; ci < 88; ++ci) acc = fmaf(ip[(size_t)ci * HW], wp[ci], acc);
    out[idx] = fmaxf(acc, 0.f);
}

// 3x3 conv 88->88, SAME, +bias, optional relu. w: [88co][88ci][3][3]
template <bool RELU>
__global__ void conv3x3_88_k(const float* __restrict__ in, const float* __restrict__ w,
                             const float* __restrict__ bias, float* __restrict__ out,
                             int H, int total) {
    int idx = blockIdx.x * blockDim.x + threadIdx.x;
    if (idx >= total) return;
    int x  = idx % H;
    int y  = (idx / H) % H;
    int co = (idx / (H * H)) % 88;
    int n  = idx / (H * H * 88);
    int HH = H * H;
    const float* ip = in + (size_t)n * 88 * HH + y * H + x;
    const float* wp = w + (size_t)co * 792;
    float acc = bias[co];
    bool vx0 = x > 0, vx2 = x < H - 1, vy0 = y > 0, vy2 = y < H - 1;
    for (int ci = 0; ci < 88; ++ci) {
        const float* ic = ip + ci * HH;
        const float* wc = wp + ci * 9;
        float i00 = (vy0 && vx0) ? ic[-H - 1] : 0.f;
        float i01 = vy0 ? ic[-H] : 0.f;
        float i02 = (vy0 && vx2) ? ic[-H + 1] : 0.f;
        float i10 = vx0 ? ic[-1] : 0.f;
        float i11 = ic[0];
        float i12 = vx2 ? ic[1] : 0.f;
        float i20 = (vy2 && vx0) ? ic[H - 1] : 0.f;
        float i21 = vy2 ? ic[H] : 0.f;
        float i22 = (vy2 && vx2) ? ic[H + 1] : 0.f;
        acc = fmaf(i00, wc[0], acc); acc = fmaf(i01, wc[1], acc); acc = fmaf(i02, wc[2], acc);
        acc = fmaf(i10, wc[3], acc); acc = fmaf(i11, wc[4], acc); acc = fmaf(i12, wc[5], acc);
        acc = fmaf(i20, wc[6], acc); acc = fmaf(i21, wc[7], acc); acc = fmaf(i22, wc[8], acc);
    }
    out[idx] = RELU ? fmaxf(acc, 0.f) : acc;
}

// transpose out-conv weight w[C9][K=792] -> wt[K][C9] for coalesced reads
__global__ void wtrans_k(const float* __restrict__ w, float* __restrict__ wt,
                         int C9, int K, int total) {
    int idx = blockIdx.x * blockDim.x + threadIdx.x;
    if (idx >= total) return;
    int c = idx / K, j = idx % K;
    wt[(size_t)j * C9 + c] = w[idx];
}

// output conv 3x3 88->C9 (+bias, optional sigmoid) with scatter into
// (B, 49104, OC) layout: row = lvl_off + (y*H+x)*9 + a, where c = a*OC + k.
// Thread order: c fastest -> fully contiguous writes per pixel.
template <bool SIG>
__global__ void head_out_k(const float* __restrict__ in, const float* __restrict__ wt,
                           const float* __restrict__ bias, float* __restrict__ outb,
                           int C9, int OC, int H, int lvl_off, int total) {
    int idx = blockIdx.x * blockDim.x + threadIdx.x;
    if (idx >= total) return;
    int c = idx % C9;
    int p = (idx / C9) % (H * H);
    int n = idx / (C9 * H * H);
    int x = p % H, y = p / H;
    int HH = H * H;
    const float* ip = in + (size_t)n * 88 * HH + y * H + x;
    float acc = bias[c];
    bool vx0 = x > 0, vx2 = x < H - 1, vy0 = y > 0, vy2 = y < H - 1;
    for (int ci = 0; ci < 88; ++ci) {
        const float* ic = ip + ci * HH;
        const float* wc = wt + (size_t)ci * 9 * C9 + c;
        float i00 = (vy0 && vx0) ? ic[-H - 1] : 0.f;
        float i01 = vy0 ? ic[-H] : 0.f;
        float i02 = (vy0 && vx2) ? ic[-H + 1] : 0.f;
        float i10 = vx0 ? ic[-1] : 0.f;
        float i11 = ic[0];
        float i12 = vx2 ? ic[1] : 0.f;
        float i20 = (vy2 && vx0) ? ic[H - 1] : 0.f;
        float i21 = vy2 ? ic[H] : 0.f;
        float i22 = (vy2 && vx2) ? ic[H + 1] : 0.f;
        acc = fmaf(i00, wc[0 * C9], acc); acc = fmaf(i01, wc[1 * C9], acc); acc = fmaf(i02, wc[2 * C9], acc);
        acc = fmaf(i10, wc[3 * C9], acc); acc = fmaf(i11, wc[4 * C9], acc); acc = fmaf(i12, wc[5 * C9], acc);
        acc = fmaf(i20, wc[6 * C9], acc); acc = fmaf(i21, wc[7 * C9], acc); acc = fmaf(i22, wc[8 * C9], acc);
    }
    if (SIG) acc = 1.f / (1.f + expf(-acc));
    int a = c / OC, k = c % OC;
    size_t row = (size_t)lvl_off + (size_t)p * 9 + a;
    outb[((size_t)n * 49104 + row) * OC + k] = acc;
}

// RetinaNet anchors for img=512, levels 3..7, 3 scales x 3 ratios.
__global__ void anchors_k(float* __restrict__ out) {
    int idx = blockIdx.x * blockDim.x + threadIdx.x;
    if (idx >= 49104) return;
    const int offs[6] = {0, 36864, 46080, 48384, 48960, 49104};
    int l = 0;
    while (idx >= offs[l + 1]) ++l;
    int j = idx - offs[l];
    int a = j % 9;
    int p = j / 9;
    int fs = 64 >> l;          // 512 / stride
    int stride = 8 << l;       // 2^(l+3)
    float size = (float)(32 << l);  // 2^(l+5)
    int ix = p % fs, iy = p / fs;
    float cx = (ix + 0.5f) * (float)stride;
    float cy = (iy + 0.5f) * (float)stride;
    const float scl[3] = {1.0f, 1.2599210498948732f, 1.5874010519681994f};
    const float sqr[3] = {0.7071067811865476f, 1.0f, 1.4142135623730951f};
    int r = a / 3, s = a % 3;
    float w = size * scl[s] / sqr[r];
    float h = size * scl[s] * sqr[r];
    float* o = out + (size_t)idx * 4;
    o[0] = cx - 0.5f * w;
    o[1] = cy - 0.5f * h;
    o[2] = cx + 0.5f * w;
    o[3] = cy + 0.5f * h;
}

// ---------------------------------------------------------------------------

extern "C" void kernel_launch(void* const* d_in, const int* in_sizes, int n_in,
                              void* d_out, int out_size, void* d_ws, size_t ws_size,
                              hipStream_t stream) {
    const float* c_in[5]  = {(const float*)d_in[0],  (const float*)d_in[3],
                             (const float*)d_in[6],  (const float*)d_in[9],
                             (const float*)d_in[12]};
    const float* lat_w[5] = {(const float*)d_in[1],  (const float*)d_in[4],
                             (const float*)d_in[7],  (const float*)d_in[10],
                             (const float*)d_in[13]};
    const float* lat_b[5] = {(const float*)d_in[2],  (const float*)d_in[5],
                             (const float*)d_in[8],  (const float*)d_in[11],
                             (const float*)d_in[14]};
    const float* bif_dw  = (const float*)d_in[15];
    const float* bif_pw  = (const float*)d_in[16];
    const float* bif_pb  = (const float*)d_in[17];
    const float* bif_fw2 = (const float*)d_in[18];
    const float* bif_fw3 = (const float*)d_in[19];
    const float* reg_tw  = (const float*)d_in[20];
    const float* reg_tb  = (const float*)d_in[21];
    const float* reg_ow  = (const float*)d_in[22];
    const float* reg_ob  = (const float*)d_in[23];
    const float* cls_tw  = (const float*)d_in[24];
    const float* cls_tb  = (const float*)d_in[25];
    const float* cls_ow  = (const float*)d_in[26];
    const float* cls_ob  = (const float*)d_in[27];

    const int HS[5]   = {64, 32, 16, 8, 4};
    const int CINL[5] = {40, 80, 112, 192, 320};
    size_t E[5];
    for (int l = 0; l < 5; ++l) E[l] = (size_t)4 * 88 * HS[l] * HS[l];

    // workspace carve-up (floats)
    float* ws = (float*)d_ws;
    size_t off = 0;
    float* PA[5]; for (int l = 0; l < 5; ++l) { PA[l] = ws + off; off += E[l]; }
    float* PB[5]; for (int l = 0; l < 5; ++l) { PB[l] = ws + off; off += E[l]; }
    float* T4 = ws + off; off += E[1];
    float* T5 = ws + off; off += E[2];
    float* T6 = ws + off; off += E[3];
    float* F  = ws + off; off += E[0];
    float* DT = ws + off; off += E[0];
    float* HX0 = ws + off; off += E[0];
    float* HX1 = ws + off; off += E[0];
    float* WT_REG = ws + off; off += (size_t)36 * 792;
    float* WT_CLS = ws + off; off += (size_t)810 * 792;
    (void)ws_size; // ~41 MB needed

    // laterals
    for (int l = 0; l < 5; ++l) {
        int total = (int)E[l];
        lateral_k<<<cdiv(total, TPB), TPB, 0, stream>>>(
            c_in[l], lat_w[l], lat_b[l], PA[l], CINL[l], HS[l] * HS[l], total);
    }

    // out-conv weight transposes
    wtrans_k<<<cdiv(36 * 792, TPB), TPB, 0, stream>>>(reg_ow, WT_REG, 36, 792, 36 * 792);
    wtrans_k<<<cdiv(810 * 792, TPB), TPB, 0, stream>>>(cls_ow, WT_CLS, 810, 792, 810 * 792);

    // anchors (output region 2)
    float* cls_base = (float*)d_out;
    float* reg_base = cls_base + (size_t)4 * 49104 * 90;
    float* anc_base = reg_base + (size_t)4 * 49104 * 4;
    anchors_k<<<cdiv(49104, TPB), TPB, 0, stream>>>(anc_base);

    // BiFPN stages
    float* cur[5] = {PA[0], PA[1], PA[2], PA[3], PA[4]};
    float* nxt[5] = {PB[0], PB[1], PB[2], PB[3], PB[4]};
    for (int s = 0; s < 3; ++s) {
        const float* dws = bif_dw + (size_t)s * 8 * 88 * 9;
        const float* pws = bif_pw + (size_t)s * 8 * 88 * 88;
        const float* pbs = bif_pb + (size_t)s * 8 * 88;
        const float* f2  = bif_fw2 + (size_t)s * 10;
        const float* f3  = bif_fw3 + (size_t)s * 9;

        auto sep = [&](int ci, float* dst, int H) {
            int total = 4 * 88 * H * H;
            dw3x3_k<<<cdiv(total, TPB), TPB, 0, stream>>>(F, dws + ci * 88 * 9, DT, H, total);
            pw_relu_k<<<cdiv(total, TPB), TPB, 0, stream>>>(
                DT, pws + ci * 88 * 88, pbs + ci * 88, dst, H * H, total);
        };

        { int H = 8;  int t = 4 * 88 * H * H;
          fuse2_up_k<<<cdiv(t, TPB), TPB, 0, stream>>>(cur[3], cur[4], f2 + 0, F, H, t);
          sep(0, T6, H); }
        { int H = 16; int t = 4 * 88 * H * H;
          fuse2_up_k<<<cdiv(t, TPB), TPB, 0, stream>>>(cur[2], T6, f2 + 2, F, H, t);
          sep(1, T5, H); }
        { int H = 32; int t = 4 * 88 * H * H;
          fuse2_up_k<<<cdiv(t, TPB), TPB, 0, stream>>>(cur[1], T5, f2 + 4, F, H, t);
          sep(2, T4, H); }
        { int H = 64; int t = 4 * 88 * H * H;
          fuse2_up_k<<<cdiv(t, TPB), TPB, 0, stream>>>(cur[0], T4, f2 + 6, F, H, t);
          sep(3, nxt[0], H); }
        { int H = 32; int t = 4 * 88 * H * H;
          fuse3_down_k<<<cdiv(t, TPB), TPB, 0, stream>>>(cur[1], T4, nxt[0], f3 + 0, F, H, t);
          sep(4, nxt[1], H); }
        { int H = 16; int t = 4 * 88 * H * H;
          fuse3_down_k<<<cdiv(t, TPB), TPB, 0, stream>>>(cur[2], T5, nxt[1], f3 + 3, F, H, t);
          sep(5, nxt[2], H); }
        { int H = 8;  int t = 4 * 88 * H * H;
          fuse3_down_k<<<cdiv(t, TPB), TPB, 0, stream>>>(cur[3], T6, nxt[2], f3 + 6, F, H, t);
          sep(6, nxt[3], H); }
        { int H = 4;  int t = 4 * 88 * H * H;
          fuse2_down_k<<<cdiv(t, TPB), TPB, 0, stream>>>(cur[4], nxt[3], f2 + 8, F, H, t);
          sep(7, nxt[4], H); }

        for (int l = 0; l < 5; ++l) { float* tp = cur[l]; cur[l] = nxt[l]; nxt[l] = tp; }
    }

    // heads
    const int LOFF[5] = {0, 36864, 46080, 48384, 48960};
    float* bufs[2] = {HX0, HX1};
    for (int l = 0; l < 5; ++l) {
        int H = HS[l];
        int total = 4 * 88 * H * H;
        int g = cdiv(total, TPB);

        // regression head
        const float* x = cur[l];
        for (int i = 0; i < 4; ++i) {
            float* y = bufs[i & 1];
            conv3x3_88_k<true><<<g, TPB, 0, stream>>>(
                x, reg_tw + (size_t)i * 88 * 792, reg_tb + i * 88, y, H, total);
            x = y;
        }
        { int t2 = 4 * H * H * 36;
          head_out_k<false><<<cdiv(t2, TPB), TPB, 0, stream>>>(
              x, WT_REG, reg_ob, reg_base, 36, 4, H, LOFF[l], t2); }

        // classification head
        x = cur[l];
        for (int i = 0; i < 4; ++i) {
            float* y = bufs[i & 1];
            conv3x3_88_k<true><<<g, TPB, 0, stream>>>(
                x, cls_tw + (size_t)i * 88 * 792, cls_tb + i * 88, y, H, total);
            x = y;
        }
        { int t2 = 4 * H * H * 810;
          head_out_k<true><<<cdiv(t2, TPB), TPB, 0, stream>>>(
              x, WT_CLS, cls_ob, cls_base, 810, 90, H, LOFF[l], t2); }
    }
}

// Round 2
// 2006.924 us; speedup vs baseline: 3.7791x; 3.7791x over previous
//
#include <hip/hip_runtime.h>
#include <math.h>

#define TPB 256
static inline int cdiv(int a, int b) { return (a + b - 1) / b; }

typedef __attribute__((ext_vector_type(8))) short short8;
typedef __attribute__((ext_vector_type(4))) float floatx4;

__device__ __forceinline__ float bf2f(ushort u) {
    union { unsigned int u; float f; } v; v.u = ((unsigned int)u) << 16; return v.f;
}
__device__ __forceinline__ ushort f2bf(float f) {
    union { float f; unsigned int u; } v; v.f = f;
    unsigned int r = (v.u + 0x7FFFu + ((v.u >> 16) & 1u)) >> 16;
    return (ushort)r;
}

// ---------------------------------------------------------------------------
// Layouts: feature maps bf16 [4][H][W][96] (channels 88 padded to 96).
// Weights pre-packed to MFMA B-fragment order:
//   Bp[(((tap*3+ks)*4+g)*Ntot + n)*8 + j]  = W[co=n][ci=ks*32+g*8+j][tap]
// ---------------------------------------------------------------------------

// pack 3x3 conv weights w[co][88ci][3][3] (co<CO) -> frag order, Ntot cols
__global__ void pack3_k(const float* __restrict__ w, ushort* __restrict__ Bp,
                        int Ntot, int CO, int total) {
    int idx = blockIdx.x * blockDim.x + threadIdx.x;
    if (idx >= total) return;
    int j = idx & 7; int t = idx >> 3;
    int n = t % Ntot; t /= Ntot;
    int g = t & 3; t >>= 2;
    int ks = t % 3; int tap = t / 3;
    int ci = ks * 32 + g * 8 + j;
    float v = (ci < 88 && n < CO) ? w[((size_t)n * 88 + ci) * 9 + tap] : 0.f;
    Bp[idx] = f2bf(v);
}

// pack all 24 BiFPN pointwise convs: pw[24][88co][88ci] -> 24 x [3][4][96][8]
__global__ void pack_pw_all_k(const float* __restrict__ pw, ushort* __restrict__ Bp,
                              int total) {
    int idx = blockIdx.x * blockDim.x + threadIdx.x;
    if (idx >= total) return;
    int cid = idx / 9216; int r = idx - cid * 9216;
    int j = r & 7; int t = r >> 3;
    int n = t % 96; t /= 96;
    int g = t & 3; int ks = t >> 2;
    int ci = ks * 32 + g * 8 + j;
    float v = (ci < 88 && n < 88) ? pw[(size_t)cid * 7744 + n * 88 + ci] : 0.f;
    Bp[idx] = f2bf(v);
}

// ---------------------------------------------------------------------------
// MFMA implicit-GEMM conv. TAPS=9: 3x3 SAME; TAPS=1: pointwise.
// In/out: bf16 NHWC96. Block: 256 thr = 4 waves (2m x 2n), tile 64x96.
// Always +bias (fp32, len 88) + ReLU.
// ---------------------------------------------------------------------------
template <int TAPS>
__global__ __launch_bounds__(256)
void conv_mfma_k(const ushort* __restrict__ in, const ushort* __restrict__ Bp,
                 const float* __restrict__ bias, ushort* __restrict__ out,
                 int H, int M) {
    const int W = H, HH = H * H;
    __shared__ ushort As[64 * 104];
    int tid = threadIdx.x;
    int m0 = blockIdx.x * 64;
    int l = tid & 63, l15 = l & 15, g = (l >> 4) & 3;
    int wave = tid >> 6, wm = wave & 1, wn = wave >> 1;
    floatx4 acc[2][3];
#pragma unroll
    for (int a = 0; a < 2; ++a)
#pragma unroll
        for (int b = 0; b < 3; ++b) acc[a][b] = (floatx4){0.f, 0.f, 0.f, 0.f};
    const short8* Bq = (const short8*)Bp;

#pragma unroll
    for (int tap = 0; tap < TAPS; ++tap) {
        const int dy = (TAPS == 1) ? 0 : (tap / 3 - 1);
        const int dx = (TAPS == 1) ? 0 : (tap % 3 - 1);
        __syncthreads();
#pragma unroll
        for (int it = 0; it < 3; ++it) {            // 64 rows * 12 chunks / 256 thr
            int c = tid + it * 256;
            int row = c / 12, cg = c - row * 12;
            int p = m0 + row;
            uint4 v = {0u, 0u, 0u, 0u};
            if (p < M) {
                int n = p / HH, pp = p - n * HH;
                int y = pp / W, x = pp - y * W;
                int sy = y + dy, sx = x + dx;
                if (sy >= 0 && sy < H && sx >= 0 && sx < W)
                    v = *(const uint4*)(in + (((size_t)n * HH + sy * W + sx) * 96 + cg * 8));
            }
            *(uint4*)(&As[row * 104 + cg * 8]) = v;
        }
        __syncthreads();
#pragma unroll
        for (int ks = 0; ks < 3; ++ks) {
            int k = ks * 32 + g * 8;
            short8 a0 = *(const short8*)(&As[(wm * 32 + l15) * 104 + k]);
            short8 a1 = *(const short8*)(&As[(wm * 32 + 16 + l15) * 104 + k]);
            int bbase = ((tap * 3 + ks) * 4 + g) * 96 + wn * 48 + l15;
#pragma unroll
            for (int nf = 0; nf < 3; ++nf) {
                short8 b = Bq[bbase + nf * 16];
                acc[0][nf] = __builtin_amdgcn_mfma_f32_16x16x32_bf16(a0, b, acc[0][nf], 0, 0, 0);
                acc[1][nf] = __builtin_amdgcn_mfma_f32_16x16x32_bf16(a1, b, acc[1][nf], 0, 0, 0);
            }
        }
    }
    float bc[3];
#pragma unroll
    for (int nf = 0; nf < 3; ++nf) {
        int c = wn * 48 + nf * 16 + l15;
        bc[nf] = (c < 88) ? bias[c] : 0.f;
    }
#pragma unroll
    for (int mf = 0; mf < 2; ++mf)
#pragma unroll
        for (int r = 0; r < 4; ++r) {
            int p = m0 + wm * 32 + mf * 16 + g * 4 + r;
            if (p >= M) continue;
#pragma unroll
            for (int nf = 0; nf < 3; ++nf) {
                int c = wn * 48 + nf * 16 + l15;
                float v = acc[mf][nf][r] + bc[nf];
                out[(size_t)p * 96 + c] = f2bf(fmaxf(v, 0.f));
            }
        }
}

// ---------------------------------------------------------------------------
// Output-head conv (3x3, 88->C9) fused with transpose/reshape scatter and
// optional sigmoid. Grid: (M/64, Ntot/96). Ntot = C9 padded to 96-multiple.
// ---------------------------------------------------------------------------
template <bool SIG>
__global__ __launch_bounds__(256)
void head_mfma_k(const ushort* __restrict__ in, const ushort* __restrict__ Bp,
                 const float* __restrict__ bias, float* __restrict__ outb,
                 int H, int M, int Ntot, int C9, int OC, int lvl_off) {
    const int W = H, HH = H * H;
    __shared__ ushort As[64 * 104];
    int tid = threadIdx.x;
    int m0 = blockIdx.x * 64;
    int n0b = blockIdx.y * 96;
    int l = tid & 63, l15 = l & 15, g = (l >> 4) & 3;
    int wave = tid >> 6, wm = wave & 1, wn = wave >> 1;
    floatx4 acc[2][3];
#pragma unroll
    for (int a = 0; a < 2; ++a)
#pragma unroll
        for (int b = 0; b < 3; ++b) acc[a][b] = (floatx4){0.f, 0.f, 0.f, 0.f};
    const short8* Bq = (const short8*)Bp;

    for (int tap = 0; tap < 9; ++tap) {
        int dy = tap / 3 - 1, dx = tap % 3 - 1;
        __syncthreads();
#pragma unroll
        for (int it = 0; it < 3; ++it) {
            int c = tid + it * 256;
            int row = c / 12, cg = c - row * 12;
            int p = m0 + row;
            uint4 v = {0u, 0u, 0u, 0u};
            if (p < M) {
                int n = p / HH, pp = p - n * HH;
                int y = pp / W, x = pp - y * W;
                int sy = y + dy, sx = x + dx;
                if (sy >= 0 && sy < H && sx >= 0 && sx < W)
                    v = *(const uint4*)(in + (((size_t)n * HH + sy * W + sx) * 96 + cg * 8));
            }
            *(uint4*)(&As[row * 104 + cg * 8]) = v;
        }
        __syncthreads();
#pragma unroll
        for (int ks = 0; ks < 3; ++ks) {
            int k = ks * 32 + g * 8;
            short8 a0 = *(const short8*)(&As[(wm * 32 + l15) * 104 + k]);
            short8 a1 = *(const short8*)(&As[(wm * 32 + 16 + l15) * 104 + k]);
            int bbase = ((tap * 3 + ks) * 4 + g) * Ntot + n0b + wn * 48 + l15;
#pragma unroll
            for (int nf = 0; nf < 3; ++nf) {
                short8 b = Bq[bbase + nf * 16];
                acc[0][nf] = __builtin_amdgcn_mfma_f32_16x16x32_bf16(a0, b, acc[0][nf], 0, 0, 0);
                acc[1][nf] = __builtin_amdgcn_mfma_f32_16x16x32_bf16(a1, b, acc[1][nf], 0, 0, 0);
            }
        }
    }
#pragma unroll
    for (int nf = 0; nf < 3; ++nf) {
        int c = n0b + wn * 48 + nf * 16 + l15;
        if (c >= C9) continue;
        float bcv = bias[c];
        int a = c / OC, kk = c - a * OC;
#pragma unroll
        for (int mf = 0; mf < 2; ++mf)
#pragma unroll
            for (int r = 0; r < 4; ++r) {
                int p = m0 + wm * 32 + mf * 16 + g * 4 + r;
                if (p >= M) continue;
                float v = acc[mf][nf][r] + bcv;
                if (SIG) v = 1.f / (1.f + expf(-v));
                int n = p / HH, pp = p - n * HH;
                outb[((size_t)n * 49104 + lvl_off + (size_t)pp * 9 + a) * OC + kk] = v;
            }
    }
}

// ---------------------------------------------------------------------------
// Elementwise glue on bf16 NHWC96
// ---------------------------------------------------------------------------

// lateral 1x1: NCHW fp32 (Cin) -> NHWC96 bf16
__global__ void lateral_k(const float* __restrict__ x, const float* __restrict__ w,
                          const float* __restrict__ b, ushort* __restrict__ out,
                          int Cin, int H, int total) {
    int idx = blockIdx.x * blockDim.x + threadIdx.x;
    if (idx >= total) return;
    int co = idx % 96, p = idx / 96;
    if (co >= 88) { out[idx] = 0; return; }
    int HH = H * H;
    int n = p / HH, pp = p - n * HH;
    const float* xp = x + (size_t)n * Cin * HH + pp;
    const float* wp = w + co * Cin;
    float acc = b[co];
    for (int ci = 0; ci < Cin; ++ci) acc = fmaf(xp[(size_t)ci * HH], wp[ci], acc);
    out[idx] = f2bf(acc);
}

__global__ void fuse2_up_k(const ushort* __restrict__ a, const ushort* __restrict__ bs,
                           const float* __restrict__ fw, ushort* __restrict__ out,
                           int H, int total) {
    int idx = blockIdx.x * blockDim.x + threadIdx.x;
    if (idx >= total) return;
    float w0 = fmaxf(fw[0], 0.f), w1 = fmaxf(fw[1], 0.f);
    float inv = 1.f / (w0 + w1 + 1e-4f);
    int c = idx % 96, p = idx / 96;
    int HH = H * H, W = H;
    int n = p / HH, pp = p - n * HH;
    int y = pp / W, x = pp - y * W;
    int Hh = H >> 1;
    float bv = bf2f(bs[(((size_t)n * Hh + (y >> 1)) * Hh + (x >> 1)) * 96 + c]);
    out[idx] = f2bf((w0 * bf2f(a[idx]) + w1 * bv) * inv);
}

__global__ void fuse2_down_k(const ushort* __restrict__ a, const ushort* __restrict__ bb,
                             const float* __restrict__ fw, ushort* __restrict__ out,
                             int H, int total) {
    int idx = blockIdx.x * blockDim.x + threadIdx.x;
    if (idx >= total) return;
    float w0 = fmaxf(fw[0], 0.f), w1 = fmaxf(fw[1], 0.f);
    float inv = 1.f / (w0 + w1 + 1e-4f);
    int c = idx % 96, p = idx / 96;
    int HH = H * H, W = H, H2 = H * 2;
    int n = p / HH, pp = p - n * HH;
    int y = pp / W, x = pp - y * W;
    const ushort* bp = bb + (((size_t)n * H2 + 2 * y) * H2 + 2 * x) * 96 + c;
    float m = fmaxf(fmaxf(bf2f(bp[0]), bf2f(bp[96])),
                    fmaxf(bf2f(bp[H2 * 96]), bf2f(bp[H2 * 96 + 96])));
    out[idx] = f2bf((w0 * bf2f(a[idx]) + w1 * m) * inv);
}

__global__ void fuse3_down_k(const ushort* __restrict__ a, const ushort* __restrict__ b2,
                             const ushort* __restrict__ cb, const float* __restrict__ fw,
                             ushort* __restrict__ out, int H, int total) {
    int idx = blockIdx.x * blockDim.x + threadIdx.x;
    if (idx >= total) return;
    float w0 = fmaxf(fw[0], 0.f), w1 = fmaxf(fw[1], 0.f), w2 = fmaxf(fw[2], 0.f);
    float inv = 1.f / (w0 + w1 + w2 + 1e-4f);
    int c = idx % 96, p = idx / 96;
    int HH = H * H, W = H, H2 = H * 2;
    int n = p / HH, pp = p - n * HH;
    int y = pp / W, x = pp - y * W;
    const ushort* cp = cb + (((size_t)n * H2 + 2 * y) * H2 + 2 * x) * 96 + c;
    float m = fmaxf(fmaxf(bf2f(cp[0]), bf2f(cp[96])),
                    fmaxf(bf2f(cp[H2 * 96]), bf2f(cp[H2 * 96 + 96])));
    out[idx] = f2bf((w0 * bf2f(a[idx]) + w1 * bf2f(b2[idx]) + w2 * m) * inv);
}

// depthwise 3x3 SAME on NHWC96; weights fp32 [88][3][3]
__global__ void dw3x3_k(const ushort* __restrict__ in, const float* __restrict__ w,
                        ushort* __restrict__ out, int H, int total) {
    int idx = blockIdx.x * blockDim.x + threadIdx.x;
    if (idx >= total) return;
    int c = idx % 96, p = idx / 96;
    if (c >= 88) { out[idx] = 0; return; }
    int HH = H * H, W = H;
    int n = p / HH, pp = p - n * HH;
    int y = pp / W, x = pp - y * W;
    const float* wp = w + c * 9;
    float acc = 0.f;
#pragma unroll
    for (int ky = 0; ky < 3; ++ky) {
        int sy = y + ky - 1;
        if (sy < 0 || sy >= H) continue;
#pragma unroll
        for (int kx = 0; kx < 3; ++kx) {
            int sx = x + kx - 1;
            if (sx < 0 || sx >= W) continue;
            acc = fmaf(bf2f(in[(((size_t)n * HH + sy * W + sx)) * 96 + c]), wp[ky * 3 + kx], acc);
        }
    }
    out[idx] = f2bf(acc);
}

// anchors (unchanged, fp32 exact)
__global__ void anchors_k(float* __restrict__ out) {
    int idx = blockIdx.x * blockDim.x + threadIdx.x;
    if (idx >= 49104) return;
    const int offs[6] = {0, 36864, 46080, 48384, 48960, 49104};
    int l = 0;
    while (idx >= offs[l + 1]) ++l;
    int j = idx - offs[l];
    int a = j % 9;
    int p = j / 9;
    int fs = 64 >> l;
    int stride = 8 << l;
    float size = (float)(32 << l);
    int ix = p % fs, iy = p / fs;
    float cx = (ix + 0.5f) * (float)stride;
    float cy = (iy + 0.5f) * (float)stride;
    const float scl[3] = {1.0f, 1.2599210498948732f, 1.5874010519681994f};
    const float sqr[3] = {0.7071067811865476f, 1.0f, 1.4142135623730951f};
    int r = a / 3, s = a % 3;
    float w = size * scl[s] / sqr[r];
    float h = size * scl[s] * sqr[r];
    float* o = out + (size_t)idx * 4;
    o[0] = cx - 0.5f * w;
    o[1] = cy - 0.5f * h;
    o[2] = cx + 0.5f * w;
    o[3] = cy + 0.5f * h;
}

// ---------------------------------------------------------------------------

extern "C" void kernel_launch(void* const* d_in, const int* in_sizes, int n_in,
                              void* d_out, int out_size, void* d_ws, size_t ws_size,
                              hipStream_t stream) {
    const float* c_in[5]  = {(const float*)d_in[0],  (const float*)d_in[3],
                             (const float*)d_in[6],  (const float*)d_in[9],
                             (const float*)d_in[12]};
    const float* lat_w[5] = {(const float*)d_in[1],  (const float*)d_in[4],
                             (const float*)d_in[7],  (const float*)d_in[10],
                             (const float*)d_in[13]};
    const float* lat_b[5] = {(const float*)d_in[2],  (const float*)d_in[5],
                             (const float*)d_in[8],  (const float*)d_in[11],
                             (const float*)d_in[14]};
    const float* bif_dw  = (const float*)d_in[15];
    const float* bif_pw  = (const float*)d_in[16];
    const float* bif_pb  = (const float*)d_in[17];
    const float* bif_fw2 = (const float*)d_in[18];
    const float* bif_fw3 = (const float*)d_in[19];
    const float* reg_tw  = (const float*)d_in[20];
    const float* reg_tb  = (const float*)d_in[21];
    const float* reg_ow  = (const float*)d_in[22];
    const float* reg_ob  = (const float*)d_in[23];
    const float* cls_tw  = (const float*)d_in[24];
    const float* cls_tb  = (const float*)d_in[25];
    const float* cls_ow  = (const float*)d_in[26];
    const float* cls_ob  = (const float*)d_in[27];

    const int HS[5] = {64, 32, 16, 8, 4};
    const int CINL[5] = {40, 80, 112, 192, 320};
    size_t Ebf[5];  // ushort elems per NHWC96 map
    for (int l = 0; l < 5; ++l) Ebf[l] = (size_t)4 * HS[l] * HS[l] * 96;

    ushort* ws = (ushort*)d_ws;
    size_t off = 0;
    ushort* PA[5]; for (int l = 0; l < 5; ++l) { PA[l] = ws + off; off += Ebf[l]; }
    ushort* PB[5]; for (int l = 0; l < 5; ++l) { PB[l] = ws + off; off += Ebf[l]; }
    ushort* T4 = ws + off; off += Ebf[1];
    ushort* T5 = ws + off; off += Ebf[2];
    ushort* T6 = ws + off; off += Ebf[3];
    ushort* F   = ws + off; off += Ebf[0];
    ushort* DT  = ws + off; off += Ebf[0];
    ushort* HX0 = ws + off; off += Ebf[0];
    ushort* HX1 = ws + off; off += Ebf[0];
    ushort* BP_PW = ws + off; off += (size_t)24 * 9216;   // 24 pointwise convs
    ushort* BP_TW = ws + off; off += (size_t)8 * 82944;   // 4 reg + 4 cls tower convs
    ushort* BP_RO = ws + off; off += (size_t)82944;       // reg out (N=96)
    ushort* BP_CO = ws + off; off += (size_t)746496;      // cls out (N=864)
    (void)ws_size; (void)n_in; (void)in_sizes; (void)out_size;

    // ---- weight packing ----
    pack_pw_all_k<<<cdiv(24 * 9216, TPB), TPB, 0, stream>>>(bif_pw, BP_PW, 24 * 9216);
    for (int i = 0; i < 4; ++i)
        pack3_k<<<cdiv(82944, TPB), TPB, 0, stream>>>(
            reg_tw + (size_t)i * 88 * 792, BP_TW + (size_t)i * 82944, 96, 88, 82944);
    for (int i = 0; i < 4; ++i)
        pack3_k<<<cdiv(82944, TPB), TPB, 0, stream>>>(
            cls_tw + (size_t)i * 88 * 792, BP_TW + (size_t)(4 + i) * 82944, 96, 88, 82944);
    pack3_k<<<cdiv(82944, TPB), TPB, 0, stream>>>(reg_ow, BP_RO, 96, 36, 82944);
    pack3_k<<<cdiv(746496, TPB), TPB, 0, stream>>>(cls_ow, BP_CO, 864, 810, 746496);

    // ---- anchors ----
    float* cls_base = (float*)d_out;
    float* reg_base = cls_base + (size_t)4 * 49104 * 90;
    float* anc_base = reg_base + (size_t)4 * 49104 * 4;
    anchors_k<<<cdiv(49104, TPB), TPB, 0, stream>>>(anc_base);

    // ---- laterals ----
    for (int l = 0; l < 5; ++l) {
        int total = (int)Ebf[l];
        lateral_k<<<cdiv(total, TPB), TPB, 0, stream>>>(
            c_in[l], lat_w[l], lat_b[l], PA[l], CINL[l], HS[l], total);
    }

    // ---- BiFPN ----
    ushort* cur[5] = {PA[0], PA[1], PA[2], PA[3], PA[4]};
    ushort* nxt[5] = {PB[0], PB[1], PB[2], PB[3], PB[4]};
    for (int s = 0; s < 3; ++s) {
        const float* dws = bif_dw + (size_t)s * 8 * 792;
        const float* pbs = bif_pb + (size_t)s * 8 * 88;
        const float* f2  = bif_fw2 + (size_t)s * 10;
        const float* f3  = bif_fw3 + (size_t)s * 9;

        auto sep = [&](int ci, ushort* dst, int H) {
            int M = 4 * H * H;
            int total = M * 96;
            dw3x3_k<<<cdiv(total, TPB), TPB, 0, stream>>>(F, dws + ci * 792, DT, H, total);
            conv_mfma_k<1><<<cdiv(M, 64), 256, 0, stream>>>(
                DT, BP_PW + (size_t)(s * 8 + ci) * 9216, pbs + ci * 88, dst, H, M);
        };

        { int H = 8;  int t = 4 * H * H * 96;
          fuse2_up_k<<<cdiv(t, TPB), TPB, 0, stream>>>(cur[3], cur[4], f2 + 0, F, H, t);
          sep(0, T6, H); }
        { int H = 16; int t = 4 * H * H * 96;
          fuse2_up_k<<<cdiv(t, TPB), TPB, 0, stream>>>(cur[2], T6, f2 + 2, F, H, t);
          sep(1, T5, H); }
        { int H = 32; int t = 4 * H * H * 96;
          fuse2_up_k<<<cdiv(t, TPB), TPB, 0, stream>>>(cur[1], T5, f2 + 4, F, H, t);
          sep(2, T4, H); }
        { int H = 64; int t = 4 * H * H * 96;
          fuse2_up_k<<<cdiv(t, TPB), TPB, 0, stream>>>(cur[0], T4, f2 + 6, F, H, t);
          sep(3, nxt[0], H); }
        { int H = 32; int t = 4 * H * H * 96;
          fuse3_down_k<<<cdiv(t, TPB), TPB, 0, stream>>>(cur[1], T4, nxt[0], f3 + 0, F, H, t);
          sep(4, nxt[1], H); }
        { int H = 16; int t = 4 * H * H * 96;
          fuse3_down_k<<<cdiv(t, TPB), TPB, 0, stream>>>(cur[2], T5, nxt[1], f3 + 3, F, H, t);
          sep(5, nxt[2], H); }
        { int H = 8;  int t = 4 * H * H * 96;
          fuse3_down_k<<<cdiv(t, TPB), TPB, 0, stream>>>(cur[3], T6, nxt[2], f3 + 6, F, H, t);
          sep(6, nxt[3], H); }
        { int H = 4;  int t = 4 * H * H * 96;
          fuse2_down_k<<<cdiv(t, TPB), TPB, 0, stream>>>(cur[4], nxt[3], f2 + 8, F, H, t);
          sep(7, nxt[4], H); }

        for (int l = 0; l < 5; ++l) { ushort* tp = cur[l]; cur[l] = nxt[l]; nxt[l] = tp; }
    }

    // ---- heads ----
    const int LOFF[5] = {0, 36864, 46080, 48384, 48960};
    ushort* bufs[2] = {HX0, HX1};
    for (int l = 0; l < 5; ++l) {
        int H = HS[l];
        int M = 4 * H * H;
        int gm = cdiv(M, 64);

        // regression tower + out
        const ushort* x = cur[l];
        for (int i = 0; i < 4; ++i) {
            conv_mfma_k<9><<<gm, 256, 0, stream>>>(
                x, BP_TW + (size_t)i * 82944, reg_tb + i * 88, bufs[i & 1], H, M);
            x = bufs[i & 1];
        }
        head_mfma_k<false><<<dim3(gm, 1), 256, 0, stream>>>(
            x, BP_RO, reg_ob, reg_base, H, M, 96, 36, 4, LOFF[l]);

        // classification tower + out
        x = cur[l];
        for (int i = 0; i < 4; ++i) {
            conv_mfma_k<9><<<gm, 256, 0, stream>>>(
                x, BP_TW + (size_t)(4 + i) * 82944, cls_tb + i * 88, bufs[i & 1], H, M);
            x = bufs[i & 1];
        }
        head_mfma_k<true><<<dim3(gm, 9), 256, 0, stream>>>(
            x, BP_CO, cls_ob, cls_base, H, M, 864, 810, 90, LOFF[l]);
    }
}

// Round 3
// 686.549 us; speedup vs baseline: 11.0471x; 2.9232x over previous
//
#include <hip/hip_runtime.h>
#include <math.h>

#define TPB 256
static inline int cdiv(int a, int b) { return (a + b - 1) / b; }

typedef __attribute__((ext_vector_type(8))) short short8;
typedef __attribute__((ext_vector_type(4))) float floatx4;

__device__ __forceinline__ float bf2f(ushort u) {
    union { unsigned int u; float f; } v; v.u = ((unsigned int)u) << 16; return v.f;
}
__device__ __forceinline__ ushort f2bf(float f) {
    union { float f; unsigned int u; } v; v.f = f;
    unsigned int r = (v.u + 0x7FFFu + ((v.u >> 16) & 1u)) >> 16;
    return (ushort)r;
}

// Concatenated pyramid layout: rows [0,16384) l0(H=64), [16384,20480) l1(H=32),
// [20480,21504) l2(H=16), [21504,21760) l3(H=8), [21760,21824) l4(H=4).
// Each row = one pixel (n,y,x) of a level, 96 bf16 channels (88 used + 8 pad=0).
#define CONC_ROWS 21824
__device__ __forceinline__ void lvl_of(int row, int& lvl, int& base) {
    lvl = 0; base = 0;
    if (row >= 16384) { lvl = 1; base = 16384; }
    if (row >= 20480) { lvl = 2; base = 20480; }
    if (row >= 21504) { lvl = 3; base = 21504; }
    if (row >= 21760) { lvl = 4; base = 21760; }
}
__constant__ int LOFFc[5] = {0, 36864, 46080, 48384, 48960};

// ---------------------------------------------------------------------------
// Weight packing. Frag order: Bp[(((tap*3+ks)*4+g)*Ntot + n)*8 + j]
//   = W[co=n][ci=ks*32+g*8+j][tap]
// ---------------------------------------------------------------------------
__global__ void pack3_k(const float* __restrict__ w, ushort* __restrict__ Bp,
                        int Ntot, int CO, int total) {
    int idx = blockIdx.x * blockDim.x + threadIdx.x;
    if (idx >= total) return;
    int j = idx & 7; int t = idx >> 3;
    int n = t % Ntot; t /= Ntot;
    int g = t & 3; t >>= 2;
    int ks = t % 3; int tap = t / 3;
    int ci = ks * 32 + g * 8 + j;
    float v = (ci < 88 && n < CO) ? w[((size_t)n * 88 + ci) * 9 + tap] : 0.f;
    Bp[idx] = f2bf(v);
}

// 8 tower convs (4 reg + 4 cls), Ntot=96, CO=88
__global__ void pack_tw8_k(const float* __restrict__ rw, const float* __restrict__ cw,
                           ushort* __restrict__ Bp) {
    int idx = blockIdx.x * blockDim.x + threadIdx.x;
    if (idx >= 8 * 82944) return;
    int i = idx / 82944; int r = idx - i * 82944;
    const float* w = (i < 4) ? rw + (size_t)i * 69696 : cw + (size_t)(i - 4) * 69696;
    int j = r & 7; int t = r >> 3;
    int n = t % 96; t /= 96;
    int g = t & 3; t >>= 2;
    int ks = t % 3; int tap = t / 3;
    int ci = ks * 32 + g * 8 + j;
    float v = (ci < 88 && n < 88) ? w[((size_t)n * 88 + ci) * 9 + tap] : 0.f;
    Bp[idx] = f2bf(v);
}

// 24 BiFPN pointwise convs -> 24 x [3ks][4g][96n][8j]
__global__ void pack_pw_all_k(const float* __restrict__ pw, ushort* __restrict__ Bp,
                              int total) {
    int idx = blockIdx.x * blockDim.x + threadIdx.x;
    if (idx >= total) return;
    int cid = idx / 9216; int r = idx - cid * 9216;
    int j = r & 7; int t = r >> 3;
    int n = t % 96; t /= 96;
    int g = t & 3; int ks = t >> 2;
    int ci = ks * 32 + g * 8 + j;
    float v = (ci < 88 && n < 88) ? pw[(size_t)cid * 7744 + n * 88 + ci] : 0.f;
    Bp[idx] = f2bf(v);
}

// 5 lateral 1x1 convs, K padded to 32: per level [KS][4g][96n][8j]
__global__ void pack_lat_k(const float* __restrict__ w3, const float* __restrict__ w4,
                           const float* __restrict__ w5, const float* __restrict__ w6,
                           const float* __restrict__ w7, ushort* __restrict__ Bp) {
    int idx = blockIdx.x * blockDim.x + threadIdx.x;
    if (idx >= 76800) return;
    int l, off;
    if (idx < 6144)       { l = 0; off = 0; }
    else if (idx < 15360) { l = 1; off = 6144; }
    else if (idx < 27648) { l = 2; off = 15360; }
    else if (idx < 46080) { l = 3; off = 27648; }
    else                  { l = 4; off = 46080; }
    const float* w = l == 0 ? w3 : l == 1 ? w4 : l == 2 ? w5 : l == 3 ? w6 : w7;
    const int cins[5] = {40, 80, 112, 192, 320};
    int Cin = cins[l];
    int r = idx - off;
    int j = r & 7; int t = r >> 3;
    int n = t % 96; t /= 96;
    int g = t & 3; int ks = t >> 2;
    int ci = ks * 32 + g * 8 + j;
    float v = (ci < Cin && n < 88) ? w[(size_t)n * Cin + ci] : 0.f;
    Bp[idx] = f2bf(v);
}

// ---------------------------------------------------------------------------
// Lateral conv as MFMA implicit GEMM: NCHW fp32 -> NHWC96 bf16, no act.
// Tile 64 pixels x 96 co; K chunks of 32. Grid = M/64 (exact).
// ---------------------------------------------------------------------------
__global__ __launch_bounds__(256)
void lateral_mfma_k(const float* __restrict__ x, const ushort* __restrict__ Bp,
                    const float* __restrict__ bias, ushort* __restrict__ out,
                    int Cin, int KS, int logHH) {
    __shared__ ushort As[64 * 40];
    int tid = threadIdx.x;
    int m0 = blockIdx.x * 64;
    int lane = tid & 63, l15 = lane & 15, g = (lane >> 4) & 3;
    int wave = tid >> 6, wm = wave & 1, wn = wave >> 1;
    floatx4 acc[2][3];
#pragma unroll
    for (int a = 0; a < 2; ++a)
#pragma unroll
        for (int b = 0; b < 3; ++b) acc[a][b] = (floatx4){0.f, 0.f, 0.f, 0.f};
    const short8* Bq = (const short8*)Bp;

    int p = m0 + lane;
    int n = p >> logHH, pp = p & ((1 << logHH) - 1);
    const float* xp = x + (((size_t)n * Cin) << logHH) + pp;

    for (int ks = 0; ks < KS; ++ks) {
        __syncthreads();
#pragma unroll
        for (int it = 0; it < 8; ++it) {
            int ciL = (tid >> 6) + it * 4;     // 0..31
            int ci = ks * 32 + ciL;
            float v = (ci < Cin) ? xp[(size_t)ci << logHH] : 0.f;
            As[lane * 40 + ciL] = f2bf(v);
        }
        __syncthreads();
        short8 a0 = *(const short8*)(&As[(wm * 32 + l15) * 40 + g * 8]);
        short8 a1 = *(const short8*)(&As[(wm * 32 + 16 + l15) * 40 + g * 8]);
        int bbase = (ks * 4 + g) * 96 + wn * 48 + l15;
#pragma unroll
        for (int nf = 0; nf < 3; ++nf) {
            short8 b = Bq[bbase + nf * 16];
            acc[0][nf] = __builtin_amdgcn_mfma_f32_16x16x32_bf16(a0, b, acc[0][nf], 0, 0, 0);
            acc[1][nf] = __builtin_amdgcn_mfma_f32_16x16x32_bf16(a1, b, acc[1][nf], 0, 0, 0);
        }
    }
    float bc[3];
#pragma unroll
    for (int nf = 0; nf < 3; ++nf) {
        int c = wn * 48 + nf * 16 + l15;
        bc[nf] = (c < 88) ? bias[c] : 0.f;
    }
#pragma unroll
    for (int mf = 0; mf < 2; ++mf)
#pragma unroll
        for (int r = 0; r < 4; ++r) {
            int pl = m0 + wm * 32 + mf * 16 + g * 4 + r;
#pragma unroll
            for (int nf = 0; nf < 3; ++nf) {
                int c = wn * 48 + nf * 16 + l15;
                out[(size_t)pl * 96 + c] = f2bf(acc[mf][nf][r] + bc[nf]);
            }
        }
}

// ---------------------------------------------------------------------------
// Fused BiFPN fuse-op + depthwise 3x3. MODE 0: 2-in up; 1: 2-in down; 2: 3-in down.
// Inputs NHWC96 bf16 level-local maps; out = dw result (pw input), pad c -> 0.
// ---------------------------------------------------------------------------
template <int MODE>
__global__ void fusedw_k(const ushort* __restrict__ a, const ushort* __restrict__ b,
                         const ushort* __restrict__ cmap, const float* __restrict__ fw,
                         const float* __restrict__ dww, ushort* __restrict__ out,
                         int logH, int total) {
    int idx = blockIdx.x * blockDim.x + threadIdx.x;
    if (idx >= total) return;
    int c = idx % 96, p = idx / 96;
    if (c >= 88) { out[idx] = 0; return; }
    int H = 1 << logH;
    int HH = H * H;
    int n = p >> (2 * logH), pp = p & (HH - 1);
    int y = pp >> logH, x = pp & (H - 1);
    float w0 = fmaxf(fw[0], 0.f), w1 = fmaxf(fw[1], 0.f);
    float w2 = (MODE == 2) ? fmaxf(fw[2], 0.f) : 0.f;
    float inv = 1.f / (w0 + w1 + w2 + 1e-4f);
    const float* wp = dww + c * 9;
    float acc = 0.f;
#pragma unroll
    for (int ky = 0; ky < 3; ++ky) {
        int sy = y + ky - 1;
        if (sy < 0 || sy >= H) continue;
#pragma unroll
        for (int kx = 0; kx < 3; ++kx) {
            int sx = x + kx - 1;
            if (sx < 0 || sx >= H) continue;
            int np = n * HH + sy * H + sx;
            float av = bf2f(a[(size_t)np * 96 + c]);
            float fv;
            if (MODE == 0) {
                int Hh = H >> 1;
                int bp = n * Hh * Hh + (sy >> 1) * Hh + (sx >> 1);
                fv = (w0 * av + w1 * bf2f(b[(size_t)bp * 96 + c])) * inv;
            } else {
                int H2 = H * 2;
                const ushort* q = (MODE == 1 ? b : cmap) +
                    ((size_t)(n * H2 * H2 + 2 * sy * H2 + 2 * sx)) * 96 + c;
                float m = fmaxf(fmaxf(bf2f(q[0]), bf2f(q[96])),
                                fmaxf(bf2f(q[H2 * 96]), bf2f(q[H2 * 96 + 96])));
                if (MODE == 1) fv = (w0 * av + w1 * m) * inv;
                else {
                    float b2v = bf2f(b[(size_t)np * 96 + c]);
                    fv = (w0 * av + w1 * b2v + w2 * m) * inv;
                }
            }
            acc = fmaf(fv, wp[ky * 3 + kx], acc);
        }
    }
    out[idx] = f2bf(acc);
}

// ---------------------------------------------------------------------------
// Pointwise 88->88 MFMA + bias + ReLU. Grid = M/64 (exact), single barrier.
// ---------------------------------------------------------------------------
__global__ __launch_bounds__(256)
void pw_mfma_k(const ushort* __restrict__ in, const ushort* __restrict__ Bp,
               const float* __restrict__ bias, ushort* __restrict__ out) {
    __shared__ ushort As[64 * 104];
    int tid = threadIdx.x;
    int m0 = blockIdx.x * 64;
    int lane = tid & 63, l15 = lane & 15, g = (lane >> 4) & 3;
    int wave = tid >> 6, wm = wave & 1, wn = wave >> 1;
    floatx4 acc[2][3];
#pragma unroll
    for (int a = 0; a < 2; ++a)
#pragma unroll
        for (int b = 0; b < 3; ++b) acc[a][b] = (floatx4){0.f, 0.f, 0.f, 0.f};
    const short8* Bq = (const short8*)Bp;
#pragma unroll
    for (int it = 0; it < 3; ++it) {
        int cc = tid + it * 256;
        int row = cc / 12, cg = cc - row * 12;
        *(uint4*)(&As[row * 104 + cg * 8]) =
            *(const uint4*)(in + (size_t)(m0 + row) * 96 + cg * 8);
    }
    __syncthreads();
#pragma unroll
    for (int ks = 0; ks < 3; ++ks) {
        int k = ks * 32 + g * 8;
        short8 a0 = *(const short8*)(&As[(wm * 32 + l15) * 104 + k]);
        short8 a1 = *(const short8*)(&As[(wm * 32 + 16 + l15) * 104 + k]);
        int bbase = (ks * 4 + g) * 96 + wn * 48 + l15;
#pragma unroll
        for (int nf = 0; nf < 3; ++nf) {
            short8 b = Bq[bbase + nf * 16];
            acc[0][nf] = __builtin_amdgcn_mfma_f32_16x16x32_bf16(a0, b, acc[0][nf], 0, 0, 0);
            acc[1][nf] = __builtin_amdgcn_mfma_f32_16x16x32_bf16(a1, b, acc[1][nf], 0, 0, 0);
        }
    }
    float bc[3];
#pragma unroll
    for (int nf = 0; nf < 3; ++nf) {
        int c = wn * 48 + nf * 16 + l15;
        bc[nf] = (c < 88) ? bias[c] : 0.f;
    }
#pragma unroll
    for (int mf = 0; mf < 2; ++mf)
#pragma unroll
        for (int r = 0; r < 4; ++r) {
            int pl = m0 + wm * 32 + mf * 16 + g * 4 + r;
#pragma unroll
            for (int nf = 0; nf < 3; ++nf) {
                int c = wn * 48 + nf * 16 + l15;
                out[(size_t)pl * 96 + c] = f2bf(fmaxf(acc[mf][nf][r] + bc[nf], 0.f));
            }
        }
}

// ---------------------------------------------------------------------------
// Tower conv 3x3 88->88 + bias + ReLU over CONCATENATED pyramid, dual-head
// (blockIdx.y: 0=reg, 1=cls). Grid (341, 2).
// ---------------------------------------------------------------------------
__global__ __launch_bounds__(256)
void tower_mfma_k(const ushort* __restrict__ inR, const ushort* __restrict__ inC,
                  const ushort* __restrict__ BpR, const ushort* __restrict__ BpC,
                  const float* __restrict__ bR, const float* __restrict__ bC,
                  ushort* __restrict__ outR, ushort* __restrict__ outC) {
    int head = blockIdx.y;
    const ushort* in = head ? inC : inR;
    const ushort* Bp = head ? BpC : BpR;
    const float* bias = head ? bC : bR;
    ushort* out = head ? outC : outR;

    __shared__ ushort As[64 * 104];
    int tid = threadIdx.x;
    int m0 = blockIdx.x * 64;
    int lvl, base; lvl_of(m0, lvl, base);
    int logW = 6 - lvl, W = 1 << logW, HH = W * W, log2HH = 2 * logW;
    int pl0 = m0 - base;
    int lane = tid & 63, l15 = lane & 15, g = (lane >> 4) & 3;
    int wave = tid >> 6, wm = wave & 1, wn = wave >> 1;
    floatx4 acc[2][3];
#pragma unroll
    for (int a = 0; a < 2; ++a)
#pragma unroll
        for (int b = 0; b < 3; ++b) acc[a][b] = (floatx4){0.f, 0.f, 0.f, 0.f};
    const short8* Bq = (const short8*)Bp;

#pragma unroll
    for (int tap = 0; tap < 9; ++tap) {
        int dy = tap / 3 - 1, dx = tap % 3 - 1;
        __syncthreads();
#pragma unroll
        for (int it = 0; it < 3; ++it) {
            int cc = tid + it * 256;
            int row = cc / 12, cg = cc - row * 12;
            int pl = pl0 + row;
            int n = pl >> log2HH, pp = pl & (HH - 1);
            int y = pp >> logW, x = pp & (W - 1);
            int sy = y + dy, sx = x + dx;
            uint4 v = {0u, 0u, 0u, 0u};
            if (sy >= 0 && sy < W && sx >= 0 && sx < W)
                v = *(const uint4*)(in + ((size_t)(base + (n << log2HH) + (sy << logW) + sx)) * 96 + cg * 8);
            *(uint4*)(&As[row * 104 + cg * 8]) = v;
        }
        __syncthreads();
#pragma unroll
        for (int ks = 0; ks < 3; ++ks) {
            int k = ks * 32 + g * 8;
            short8 a0 = *(const short8*)(&As[(wm * 32 + l15) * 104 + k]);
            short8 a1 = *(const short8*)(&As[(wm * 32 + 16 + l15) * 104 + k]);
            int bbase = ((tap * 3 + ks) * 4 + g) * 96 + wn * 48 + l15;
#pragma unroll
            for (int nf = 0; nf < 3; ++nf) {
                short8 b = Bq[bbase + nf * 16];
                acc[0][nf] = __builtin_amdgcn_mfma_f32_16x16x32_bf16(a0, b, acc[0][nf], 0, 0, 0);
                acc[1][nf] = __builtin_amdgcn_mfma_f32_16x16x32_bf16(a1, b, acc[1][nf], 0, 0, 0);
            }
        }
    }
    float bc[3];
#pragma unroll
    for (int nf = 0; nf < 3; ++nf) {
        int c = wn * 48 + nf * 16 + l15;
        bc[nf] = (c < 88) ? bias[c] : 0.f;
    }
#pragma unroll
    for (int mf = 0; mf < 2; ++mf)
#pragma unroll
        for (int r = 0; r < 4; ++r) {
            int pl = m0 + wm * 32 + mf * 16 + g * 4 + r;
#pragma unroll
            for (int nf = 0; nf < 3; ++nf) {
                int c = wn * 48 + nf * 16 + l15;
                out[(size_t)pl * 96 + c] = f2bf(fmaxf(acc[mf][nf][r] + bc[nf], 0.f));
            }
        }
}

// ---------------------------------------------------------------------------
// Output head conv 3x3 (88->C9) over concatenated pyramid, fused scatter to
// (B, 49104, OC) + optional sigmoid. Grid (341, Ntot/96).
// ---------------------------------------------------------------------------
template <bool SIG>
__global__ __launch_bounds__(256)
void head_out_all_k(const ushort* __restrict__ in, const ushort* __restrict__ Bp,
                    const float* __restrict__ bias, float* __restrict__ outb,
                    int Ntot, int C9, int OC) {
    __shared__ ushort As[64 * 104];
    int tid = threadIdx.x;
    int m0 = blockIdx.x * 64;
    int n0b = blockIdx.y * 96;
    int lvl, base; lvl_of(m0, lvl, base);
    int logW = 6 - lvl, W = 1 << logW, HH = W * W, log2HH = 2 * logW;
    int pl0 = m0 - base;
    int lane = tid & 63, l15 = lane & 15, g = (lane >> 4) & 3;
    int wave = tid >> 6, wm = wave & 1, wn = wave >> 1;
    floatx4 acc[2][3];
#pragma unroll
    for (int a = 0; a < 2; ++a)
#pragma unroll
        for (int b = 0; b < 3; ++b) acc[a][b] = (floatx4){0.f, 0.f, 0.f, 0.f};
    const short8* Bq = (const short8*)Bp;

    for (int tap = 0; tap < 9; ++tap) {
        int dy = tap / 3 - 1, dx = tap % 3 - 1;
        __syncthreads();
#pragma unroll
        for (int it = 0; it < 3; ++it) {
            int cc = tid + it * 256;
            int row = cc / 12, cg = cc - row * 12;
            int pl = pl0 + row;
            int n = pl >> log2HH, pp = pl & (HH - 1);
            int y = pp >> logW, x = pp & (W - 1);
            int sy = y + dy, sx = x + dx;
            uint4 v = {0u, 0u, 0u, 0u};
            if (sy >= 0 && sy < W && sx >= 0 && sx < W)
                v = *(const uint4*)(in + ((size_t)(base + (n << log2HH) + (sy << logW) + sx)) * 96 + cg * 8);
            *(uint4*)(&As[row * 104 + cg * 8]) = v;
        }
        __syncthreads();
#pragma unroll
        for (int ks = 0; ks < 3; ++ks) {
            int k = ks * 32 + g * 8;
            short8 a0 = *(const short8*)(&As[(wm * 32 + l15) * 104 + k]);
            short8 a1 = *(const short8*)(&As[(wm * 32 + 16 + l15) * 104 + k]);
            int bbase = ((tap * 3 + ks) * 4 + g) * Ntot + n0b + wn * 48 + l15;
#pragma unroll
            for (int nf = 0; nf < 3; ++nf) {
                short8 b = Bq[bbase + nf * 16];
                acc[0][nf] = __builtin_amdgcn_mfma_f32_16x16x32_bf16(a0, b, acc[0][nf], 0, 0, 0);
                acc[1][nf] = __builtin_amdgcn_mfma_f32_16x16x32_bf16(a1, b, acc[1][nf], 0, 0, 0);
            }
        }
    }
#pragma unroll
    for (int nf = 0; nf < 3; ++nf) {
        int c = n0b + wn * 48 + nf * 16 + l15;
        if (c >= C9) continue;
        float bcv = bias[c];
        int a = c / OC, kk = c - a * OC;
#pragma unroll
        for (int mf = 0; mf < 2; ++mf)
#pragma unroll
            for (int r = 0; r < 4; ++r) {
                int pl = pl0 + wm * 32 + mf * 16 + g * 4 + r;
                int n = pl >> log2HH, pp = pl & (HH - 1);
                float v = acc[mf][nf][r] + bcv;
                if (SIG) v = 1.f / (1.f + expf(-v));
                outb[((size_t)n * 49104 + LOFFc[lvl] + (size_t)pp * 9 + a) * OC + kk] = v;
            }
    }
}

// ---------------------------------------------------------------------------
__global__ void anchors_k(float* __restrict__ out) {
    int idx = blockIdx.x * blockDim.x + threadIdx.x;
    if (idx >= 49104) return;
    const int offs[6] = {0, 36864, 46080, 48384, 48960, 49104};
    int l = 0;
    while (idx >= offs[l + 1]) ++l;
    int j = idx - offs[l];
    int a = j % 9;
    int p = j / 9;
    int fs = 64 >> l;
    int stride = 8 << l;
    float size = (float)(32 << l);
    int ix = p % fs, iy = p / fs;
    float cx = (ix + 0.5f) * (float)stride;
    float cy = (iy + 0.5f) * (float)stride;
    const float scl[3] = {1.0f, 1.2599210498948732f, 1.5874010519681994f};
    const float sqr[3] = {0.7071067811865476f, 1.0f, 1.4142135623730951f};
    int r = a / 3, s = a % 3;
    float w = size * scl[s] / sqr[r];
    float h = size * scl[s] * sqr[r];
    float* o = out + (size_t)idx * 4;
    o[0] = cx - 0.5f * w;
    o[1] = cy - 0.5f * h;
    o[2] = cx + 0.5f * w;
    o[3] = cy + 0.5f * h;
}

// ---------------------------------------------------------------------------

extern "C" void kernel_launch(void* const* d_in, const int* in_sizes, int n_in,
                              void* d_out, int out_size, void* d_ws, size_t ws_size,
                              hipStream_t stream) {
    const float* c_in[5]  = {(const float*)d_in[0],  (const float*)d_in[3],
                             (const float*)d_in[6],  (const float*)d_in[9],
                             (const float*)d_in[12]};
    const float* lat_w[5] = {(const float*)d_in[1],  (const float*)d_in[4],
                             (const float*)d_in[7],  (const float*)d_in[10],
                             (const float*)d_in[13]};
    const float* lat_b[5] = {(const float*)d_in[2],  (const float*)d_in[5],
                             (const float*)d_in[8],  (const float*)d_in[11],
                             (const float*)d_in[14]};
    const float* bif_dw  = (const float*)d_in[15];
    const float* bif_pw  = (const float*)d_in[16];
    const float* bif_pb  = (const float*)d_in[17];
    const float* bif_fw2 = (const float*)d_in[18];
    const float* bif_fw3 = (const float*)d_in[19];
    const float* reg_tw  = (const float*)d_in[20];
    const float* reg_tb  = (const float*)d_in[21];
    const float* reg_ow  = (const float*)d_in[22];
    const float* reg_ob  = (const float*)d_in[23];
    const float* cls_tw  = (const float*)d_in[24];
    const float* cls_tb  = (const float*)d_in[25];
    const float* cls_ow  = (const float*)d_in[26];
    const float* cls_ob  = (const float*)d_in[27];

    const int HS[5]   = {64, 32, 16, 8, 4};
    const int CINL[5] = {40, 80, 112, 192, 320};
    const int KSL[5]  = {2, 3, 4, 6, 10};
    const int LATO[5] = {0, 6144, 15360, 27648, 46080};
    const int ROFF[5] = {0, 16384, 20480, 21504, 21760};
    const int ML[5]   = {16384, 4096, 1024, 256, 64};
    const size_t CONC = (size_t)CONC_ROWS * 96;

    ushort* ws = (ushort*)d_ws;
    size_t off = 0;
    ushort* CA = ws + off; off += CONC;          // BiFPN ping
    ushort* CB = ws + off; off += CONC;          // BiFPN pong
    ushort* T4 = ws + off; off += (size_t)4096 * 96;
    ushort* T5 = ws + off; off += (size_t)1024 * 96;
    ushort* T6 = ws + off; off += (size_t)256 * 96;
    ushort* DT = ws + off; off += (size_t)16384 * 96;  // dw temp (max level)
    ushort* HXR0 = ws + off; off += CONC;
    ushort* HXR1 = ws + off; off += CONC;
    ushort* HXC0 = ws + off; off += CONC;
    ushort* HXC1 = ws + off; off += CONC;
    ushort* BP_PW  = ws + off; off += (size_t)24 * 9216;
    ushort* BP_TW  = ws + off; off += (size_t)8 * 82944;
    ushort* BP_RO  = ws + off; off += (size_t)82944;
    ushort* BP_CO  = ws + off; off += (size_t)746496;
    ushort* BP_LAT = ws + off; off += (size_t)76800;
    (void)ws_size; (void)n_in; (void)in_sizes; (void)out_size;

    // ---- packing (5 dispatches) ----
    pack_pw_all_k<<<cdiv(24 * 9216, TPB), TPB, 0, stream>>>(bif_pw, BP_PW, 24 * 9216);
    pack_tw8_k<<<cdiv(8 * 82944, TPB), TPB, 0, stream>>>(reg_tw, cls_tw, BP_TW);
    pack3_k<<<cdiv(82944, TPB), TPB, 0, stream>>>(reg_ow, BP_RO, 96, 36, 82944);
    pack3_k<<<cdiv(746496, TPB), TPB, 0, stream>>>(cls_ow, BP_CO, 864, 810, 746496);
    pack_lat_k<<<cdiv(76800, TPB), TPB, 0, stream>>>(
        lat_w[0], lat_w[1], lat_w[2], lat_w[3], lat_w[4], BP_LAT);

    // ---- anchors ----
    float* cls_base = (float*)d_out;
    float* reg_base = cls_base + (size_t)4 * 49104 * 90;
    float* anc_base = reg_base + (size_t)4 * 49104 * 4;
    anchors_k<<<cdiv(49104, TPB), TPB, 0, stream>>>(anc_base);

    // ---- laterals (MFMA) ----
    for (int l = 0; l < 5; ++l) {
        int logHH = 2 * (6 - l);
        lateral_mfma_k<<<ML[l] / 64, 256, 0, stream>>>(
            c_in[l], BP_LAT + LATO[l], lat_b[l], CA + (size_t)ROFF[l] * 96,
            CINL[l], KSL[l], logHH);
    }

    // ---- BiFPN ----
    ushort* cur = CA; ushort* nxt = CB;
    for (int s = 0; s < 3; ++s) {
        const float* dws = bif_dw + (size_t)s * 8 * 792;
        const float* pbs = bif_pb + (size_t)s * 8 * 88;
        const float* f2  = bif_fw2 + (size_t)s * 10;
        const float* f3  = bif_fw3 + (size_t)s * 9;
        auto LP = [&](ushort* buf, int l) { return buf + (size_t)ROFF[l] * 96; };
        auto pw = [&](int ci, const ushort* src, ushort* dst, int l) {
            pw_mfma_k<<<ML[l] / 64, 256, 0, stream>>>(
                src, BP_PW + (size_t)(s * 8 + ci) * 9216, pbs + ci * 88, dst);
        };

        // step 0: p6t (H=8)
        { int l = 3, t = ML[l] * 96;
          fusedw_k<0><<<cdiv(t, TPB), TPB, 0, stream>>>(
              LP(cur, 3), LP(cur, 4), nullptr, f2 + 0, dws + 0 * 792, DT, 6 - l, t);
          pw(0, DT, T6, l); }
        // step 1: p5t (H=16)
        { int l = 2, t = ML[l] * 96;
          fusedw_k<0><<<cdiv(t, TPB), TPB, 0, stream>>>(
              LP(cur, 2), T6, nullptr, f2 + 2, dws + 1 * 792, DT, 6 - l, t);
          pw(1, DT, T5, l); }
        // step 2: p4t (H=32)
        { int l = 1, t = ML[l] * 96;
          fusedw_k<0><<<cdiv(t, TPB), TPB, 0, stream>>>(
              LP(cur, 1), T5, nullptr, f2 + 4, dws + 2 * 792, DT, 6 - l, t);
          pw(2, DT, T4, l); }
        // step 3: p3o (H=64)
        { int l = 0, t = ML[l] * 96;
          fusedw_k<0><<<cdiv(t, TPB), TPB, 0, stream>>>(
              LP(cur, 0), T4, nullptr, f2 + 6, dws + 3 * 792, DT, 6 - l, t);
          pw(3, DT, LP(nxt, 0), l); }
        // step 4: p4o (H=32)
        { int l = 1, t = ML[l] * 96;
          fusedw_k<2><<<cdiv(t, TPB), TPB, 0, stream>>>(
              LP(cur, 1), T4, LP(nxt, 0), f3 + 0, dws + 4 * 792, DT, 6 - l, t);
          pw(4, DT, LP(nxt, 1), l); }
        // step 5: p5o (H=16)
        { int l = 2, t = ML[l] * 96;
          fusedw_k<2><<<cdiv(t, TPB), TPB, 0, stream>>>(
              LP(cur, 2), T5, LP(nxt, 1), f3 + 3, dws + 5 * 792, DT, 6 - l, t);
          pw(5, DT, LP(nxt, 2), l); }
        // step 6: p6o (H=8)
        { int l = 3, t = ML[l] * 96;
          fusedw_k<2><<<cdiv(t, TPB), TPB, 0, stream>>>(
              LP(cur, 3), T6, LP(nxt, 2), f3 + 6, dws + 6 * 792, DT, 6 - l, t);
          pw(6, DT, LP(nxt, 3), l); }
        // step 7: p7o (H=4)
        { int l = 4, t = ML[l] * 96;
          fusedw_k<1><<<cdiv(t, TPB), TPB, 0, stream>>>(
              LP(cur, 4), LP(nxt, 3), nullptr, f2 + 8, dws + 7 * 792, DT, 6 - l, t);
          pw(7, DT, LP(nxt, 4), l); }

        ushort* tp = cur; cur = nxt; nxt = tp;
    }

    // ---- heads: dual towers over concatenated pyramid ----
    ushort* hxr[2] = {HXR0, HXR1};
    ushort* hxc[2] = {HXC0, HXC1};
    const ushort* xr = cur;
    const ushort* xc = cur;
    const int GB = CONC_ROWS / 64;  // 341
    for (int i = 0; i < 4; ++i) {
        tower_mfma_k<<<dim3(GB, 2), 256, 0, stream>>>(
            xr, xc, BP_TW + (size_t)i * 82944, BP_TW + (size_t)(4 + i) * 82944,
            reg_tb + i * 88, cls_tb + i * 88, hxr[i & 1], hxc[i & 1]);
        xr = hxr[i & 1]; xc = hxc[i & 1];
    }
    head_out_all_k<false><<<dim3(GB, 1), 256, 0, stream>>>(
        xr, BP_RO, reg_ob, reg_base, 96, 36, 4);
    head_out_all_k<true><<<dim3(GB, 9), 256, 0, stream>>>(
        xc, BP_CO, cls_ob, cls_base, 864, 810, 90);
}